// Round 5
// baseline (356.131 us; speedup 1.0000x reference)
//
#include <hip/hip_runtime.h>
#include <hip/hip_bf16.h>

#define HC 256

typedef __attribute__((ext_vector_type(8))) short bf16x8;
typedef __attribute__((ext_vector_type(8))) unsigned short u16x8;
typedef __attribute__((ext_vector_type(4))) float f32x4;
typedef __attribute__((ext_vector_type(2))) float f32x2;

__device__ __forceinline__ void gl_lds16(const void* g, void* l) {
  __builtin_amdgcn_global_load_lds(
      (const __attribute__((address_space(1))) unsigned int*)g,
      (__attribute__((address_space(3))) unsigned int*)l, 16, 0, 0);
}

// ==== bf16 weight casts (both layers) + dst-degree histogram, one kernel ===
__device__ __forceinline__ void cast_w_one(const float* Wl, const float* Wr,
                                           ushort* WT, int F, int idx) {
  int col = idx / F, f = idx - col * F;
  float v = (col < 256) ? Wl[col * F + f] : Wr[(col - 256) * F + f];
  __hip_bfloat16 h = __float2bfloat16(v);
  WT[(size_t)col * F + f] = *(ushort*)&h;
}

__global__ void k_weights_hist(const float* __restrict__ Wl1, const float* __restrict__ Wr1,
                               ushort* __restrict__ WT1, const float* __restrict__ Wl2,
                               const float* __restrict__ Wr2, ushort* __restrict__ WT2,
                               const int* __restrict__ ei, int* __restrict__ deg, int E_) {
  int idx = blockIdx.x * blockDim.x + threadIdx.x;
  const int t1 = 512 * 128, t2 = 512 * 64;
  if (idx < t1) {
    cast_w_one(Wl1, Wr1, WT1, 128, idx);
  } else if (idx < t1 + t2) {
    cast_w_one(Wl2, Wr2, WT2, 64, idx - t1);
  } else {
    int e = idx - t1 - t2;
    if (e < E_) atomicAdd(&deg[ei[E_ + e]], 1);
  }
}

// ======== MFMA GEMM: K-pipelined, disjoint LDS buffers per K-step ==========
// 4 waves, 128x128 block tile, 64x64 wave tile, BK=64.
template <int F>
__global__ __launch_bounds__(256) void gemm_mfma(const ushort* __restrict__ A,
                                                 const ushort* __restrict__ WT,
                                                 ushort* __restrict__ xlb,
                                                 ushort* __restrict__ xrb, int n_nodes) {
  constexpr int NSTEP = F / 64;
  constexpr int SM = (2 * NSTEP * 8192 > 17408) ? 2 * NSTEP * 8192 : 17408;
  __shared__ __align__(16) ushort smem[SM];
  const int tid = threadIdx.x;
  const int wv = tid >> 6, lane = tid & 63;
  const int m16 = lane & 15, quad = lane >> 4;
  const int col0 = blockIdx.x * 128;  // 0,1 -> xl ; 2,3 -> xr
  const int row0 = blockIdx.y * 128;
  const int wm = (wv >> 1) * 64, wn = (wv & 1) * 64;

  f32x4 acc[4][4];
#pragma unroll
  for (int i = 0; i < 4; ++i)
#pragma unroll
    for (int j = 0; j < 4; ++j) acc[i][j] = (f32x4){0.f, 0.f, 0.f, 0.f};

  auto load_step = [&](int s) {
    ushort* As = smem + s * 16384;
    ushort* Bs = As + 8192;
    const int khat = s * 64;
#pragma unroll
    for (int t = 0; t < 4; ++t) {
      const int sl16 = tid + 256 * t;  // LDS slot (16B units), linear in lane
      const int row = sl16 >> 3, sl = sl16 & 7;
      const int gch = sl ^ (row & 7);  // swizzle on the GLOBAL address
      const int grow = row0 + row;
      if (grow < n_nodes)
        gl_lds16(A + (size_t)grow * F + khat + gch * 8, As + sl16 * 8);
      gl_lds16(WT + (size_t)(col0 + row) * F + khat + gch * 8, Bs + sl16 * 8);
    }
  };

  auto mfma_step = [&](int s) {
    ushort* As = smem + s * 16384;
    ushort* Bs = As + 8192;
#pragma unroll
    for (int kh = 0; kh < 2; ++kh) {
      bf16x8 af[4], bf[4];
#pragma unroll
      for (int i = 0; i < 4; ++i) {
        const int row = wm + i * 16 + m16;
        const int slot = (kh * 4 + quad) ^ (row & 7);
        af[i] = *(bf16x8*)&As[row * 64 + slot * 8];
      }
#pragma unroll
      for (int j = 0; j < 4; ++j) {
        const int col = wn + j * 16 + m16;
        const int slot = (kh * 4 + quad) ^ (col & 7);
        bf[j] = *(bf16x8*)&Bs[col * 64 + slot * 8];
      }
#pragma unroll
      for (int i = 0; i < 4; ++i)
#pragma unroll
        for (int j = 0; j < 4; ++j)
          acc[i][j] =
              __builtin_amdgcn_mfma_f32_16x16x32_bf16(af[i], bf[j], acc[i][j], 0, 0, 0);
    }
  };

  load_step(0);
  __syncthreads();
  if (NSTEP > 1) load_step(1);  // DMAs overlap mfma_step(0)
  mfma_step(0);
  if (NSTEP > 1) {
    __syncthreads();  // drains step-1 loads (had mfma(0) time to land)
    mfma_step(1);
  }

  // ---- epilogue: acc -> bf16 -> LDS (pitch 136) -> coalesced 16B stores ----
  __syncthreads();  // all LDS reads done; safe to alias with Ct
  ushort* Ct = smem;
#pragma unroll
  for (int i = 0; i < 4; ++i) {
#pragma unroll
    for (int r = 0; r < 4; ++r) {
      const int row = wm + i * 16 + quad * 4 + r;
#pragma unroll
      for (int j = 0; j < 4; ++j) {
        __hip_bfloat16 h = __float2bfloat16(acc[i][j][r]);
        Ct[row * 136 + wn + j * 16 + m16] = *(ushort*)&h;
      }
    }
  }
  __syncthreads();
  const bool is_xl = (col0 < 256);
  ushort* dst = is_xl ? xlb : xrb;
  const int cb = is_xl ? col0 : (col0 - 256);
  const int chunk = tid & 15;  // 16B chunk within the 256B row
#pragma unroll
  for (int it = 0; it < 8; ++it) {
    const int row = (tid >> 4) + 16 * it;
    const int grow = row0 + row;
    int4 v = *(int4*)&Ct[row * 136 + chunk * 8];
    if (grow < n_nodes)
      *(int4*)(dst + (size_t)grow * 256 + cb + chunk * 8) = v;
  }
}

// ================= CSR build (edges bucketed by dst) =======================
__global__ void k_scan_local(const int* __restrict__ deg, int* __restrict__ rowstart,
                             int* __restrict__ partial, int n) {
  __shared__ int a[256], b[256];
  const int t = threadIdx.x;
  const int i = blockIdx.x * 256 + t;
  const int v = (i < n) ? deg[i] : 0;
  a[t] = v;
  __syncthreads();
  int* cur = a;
  int* nxt = b;
  for (int off = 1; off < 256; off <<= 1) {
    int x = cur[t];
    if (t >= off) x += cur[t - off];
    nxt[t] = x;
    __syncthreads();
    int* tmp = cur; cur = nxt; nxt = tmp;
  }
  const int incl = cur[t];
  if (i < n) rowstart[i] = incl - v;
  if (t == 255) partial[blockIdx.x] = incl;
}

// merged: every block redundantly scans the block-sums (nblk<=256), adds its
// exclusive prefix, writes rowstart+cursor; block 0 zero-fills the CSR pad.
__global__ void k_scan_final(const int* __restrict__ partial, int nblk,
                             int* __restrict__ rowstart, int* __restrict__ cursor,
                             float4* __restrict__ sea, int n, int E_) {
  __shared__ int a[256], b[256];
  const int t = threadIdx.x;
  const int v = (t < nblk) ? partial[t] : 0;
  a[t] = v;
  __syncthreads();
  int* cur = a;
  int* nxt = b;
  for (int off = 1; off < 256; off <<= 1) {
    int x = cur[t];
    if (t >= off) x += cur[t - off];
    nxt[t] = x;
    __syncthreads();
    int* tmp = cur; cur = nxt; nxt = tmp;
  }
  const int boff = (blockIdx.x > 0) ? cur[blockIdx.x - 1] : 0;
  const int i = blockIdx.x * 256 + t;
  if (i < n) {
    int vv = rowstart[i] + boff;
    rowstart[i] = vv;
    cursor[i] = vv;
  }
  if (i == 0) rowstart[n] = E_;
  if (blockIdx.x == 0 && t < 8) sea[E_ + t] = make_float4(0.f, 0.f, 0.f, 0.f);
}

// ==== fused: cast x -> bf16 A AND CSR edge scatter (src packed in sea.w) ===
__global__ void k_prep(const float* __restrict__ x, ushort* __restrict__ A,
                       const int* __restrict__ ei, const float* __restrict__ ea,
                       int* __restrict__ cursor, float4* __restrict__ sea,
                       int n, int E_) {
  const int nx8 = n * 16;  // 8 elements per thread
  int idx = blockIdx.x * blockDim.x + threadIdx.x;
  if (idx < nx8) {
    const float4* xp = (const float4*)x + (size_t)idx * 2;
    float4 v0 = xp[0], v1 = xp[1];
    float vv[8] = {v0.x, v0.y, v0.z, v0.w, v1.x, v1.y, v1.z, v1.w};
    __align__(16) ushort hb[8];
#pragma unroll
    for (int j = 0; j < 8; ++j) {
      __hip_bfloat16 h = __float2bfloat16(vv[j]);
      hb[j] = *(ushort*)&h;
    }
    *(int4*)(A + (size_t)idx * 8) = *(int4*)hb;
  } else {
    int e = idx - nx8;
    if (e < E_) {
      int dst = ei[E_ + e];
      int pos = atomicAdd(&cursor[dst], 1);
      sea[pos] = make_float4(ea[e * 3], ea[e * 3 + 1], ea[e * 3 + 2],
                             __int_as_float(ei[e]));
    }
  }
}

// ================= fused per-destination attention =========================
// ONE wave per workgroup; HALF-WAVE DST PAIRING: lanes 0-31 process dst d,
// lanes 32-63 process dst d+1 (independent gather streams; every VALU inst
// covers 2 edges). Each lane holds 8 channels (ushort8 = 16B gathers,
// 8 lanes/head). Same proven 4-edge pipeline; branches are half-uniform ->
// exec-masked, no extra per-edge bookkeeping. 8-lane head reduce via DPP
// (quad_perm xor1/xor2 + row_half_mirror). Logit: att·lrelu(s) =
// 0.6·att·(s + (2/3)|s|), at6 pre-scaled by log2(e) so w = exp2(p).
__device__ __forceinline__ float dpp_add8(float p) {
  p += __int_as_float(__builtin_amdgcn_update_dpp(
      0, __float_as_int(p), 0xB1, 0xF, 0xF, true));   // quad_perm [1,0,3,2] = xor1
  p += __int_as_float(__builtin_amdgcn_update_dpp(
      0, __float_as_int(p), 0x4E, 0xF, 0xF, true));   // quad_perm [2,3,0,1] = xor2
  p += __int_as_float(__builtin_amdgcn_update_dpp(
      0, __float_as_int(p), 0x141, 0xF, 0xF, true));  // row_half_mirror (8-lane)
  return p;
}

__device__ __forceinline__ void expand8(const u16x8& v, f32x2* o) {
#pragma unroll
  for (int t = 0; t < 4; ++t) {
    o[t].x = __uint_as_float((unsigned)v[2 * t] << 16);
    o[t].y = __uint_as_float((unsigned)v[2 * t + 1] << 16);
  }
}

__device__ __forceinline__ void edge_step2(
    const u16x8& lu, const float4& eav, const f32x2* we0, const f32x2* we1,
    const f32x2* we2, const f32x2* at6, const f32x2* xrl,
    f32x2* num, float& den) {
  f32x2 la[4];
  expand8(lu, la);
  f32x2 pv = {0.f, 0.f};
#pragma unroll
  for (int j = 0; j < 4; ++j) {
    f32x2 t = xrl[j] + we0[j] * eav.x;  // fma chain rooted at xr
    t = t + we1[j] * eav.y;
    t = t + we2[j] * eav.z;
    f32x2 s = t + la[j];
    f32x2 u;
    u.x = fmaf(fabsf(s.x), 0.66666667f, s.x);  // s + (2/3)|s|; abs is free
    u.y = fmaf(fabsf(s.y), 0.66666667f, s.y);
    pv = pv + at6[j] * u;
  }
  float p = pv.x + pv.y;
  p = dpp_add8(p);           // sum over the 8-lane head group
  const float w = exp2f(p);  // at6 carries 0.6*log2(e); |logit| small
  den += w;
#pragma unroll
  for (int j = 0; j < 4; ++j) num[j] = num[j] + (f32x2){w, w} * la[j];
}

template <int MODE>
__global__ __launch_bounds__(64, 4) void fused_attn(
    const ushort* __restrict__ xlb, const ushort* __restrict__ xrb,
    const int* __restrict__ rowstart, const float4* __restrict__ sea,
    const float* __restrict__ We, const float* __restrict__ att,
    const float* __restrict__ bias, const float* __restrict__ pw,
    float* __restrict__ out, ushort* __restrict__ outs, int n, int chp) {
  const int lane = threadIdx.x;
  const int half = lane >> 5;   // 0: even dst, 1: odd dst
  const int hl = lane & 31;     // lane within half; channels r = 8*hl + j
  const int d0 = blockIdx.x * (2 * chp);
  if (d0 >= n) return;

  // ---- prologue: per-lane weights for 8 channels (vector loads) ----
  float wf[24];
  {
    const float4* Wq = (const float4*)We + 6 * hl;  // rows 8hl..8hl+7, 3 floats each
#pragma unroll
    for (int t = 0; t < 6; ++t) *(float4*)&wf[4 * t] = Wq[t];
  }
  float af[8];
  {
    const float4* Aq = (const float4*)att + 2 * hl;
    *(float4*)&af[0] = Aq[0];
    *(float4*)&af[4] = Aq[1];
  }
  f32x2 we0[4], we1[4], we2[4], at6[4];
  const float C6 = 0.6f * 1.4426950408889634f;
#pragma unroll
  for (int j = 0; j < 8; ++j) {
    ((float*)we0)[j] = wf[3 * j + 0];
    ((float*)we1)[j] = wf[3 * j + 1];
    ((float*)we2)[j] = wf[3 * j + 2];
    ((float*)at6)[j] = af[j] * C6;
  }
  const int cb8 = 8 * (hl & 7);  // channel base for the store lanes (hl<8)
  const float4 biasA = *(const float4*)&bias[cb8];
  const float4 biasB = *(const float4*)&bias[cb8 + 4];
  float4 pwA = {0.f, 0.f, 0.f, 0.f}, pwB = {0.f, 0.f, 0.f, 0.f};
  if (MODE == 1) {
    pwA = *(const float4*)&pw[cb8];
    pwB = *(const float4*)&pw[cb8 + 4];
  }

#define GAT(e_) (*(const u16x8*)&xlb[(size_t)(unsigned)__float_as_int((e_).w) * 256 + hl * 8])

  for (int k = 0; k < chp; ++k) {
    const int dd = d0 + 2 * k + half;  // per-half dst
    const bool dv = dd < n;
    const int dc = dv ? dd : n - 1;    // clamp for safe loads

    u16x8 xu = *(const u16x8*)&xrb[(size_t)dc * 256 + hl * 8];
    f32x2 xrl[4];
    expand8(xu, xrl);

    int pos = rowstart[dc];
    const int end = dv ? rowstart[dc + 1] : pos;
    f32x2 num[4] = {{0.f, 0.f}, {0.f, 0.f}, {0.f, 0.f}, {0.f, 0.f}};
    float den = 0.f;

    if (pos < end) {  // half-uniform; exhausted half is exec-masked off
      // CSR padded by 8 zero entries past E: over-read safe. src in sea.w.
      float4 e0 = sea[pos], e1 = sea[pos + 1], e2 = sea[pos + 2], e3 = sea[pos + 3];
      u16x8 g0 = GAT(e0), g1 = GAT(e1), g2 = GAT(e2), g3 = GAT(e3);

      while (pos + 4 <= end) {
        u16x8 h0 = g0, h1 = g1, h2 = g2, h3 = g3;
        float4 f0 = e0, f1 = e1, f2 = e2, f3 = e3;
        if (pos + 4 < end) {  // half-uniform: prefetch only if more edges
          f0 = sea[pos + 4];
          f1 = sea[pos + 5];
          f2 = sea[pos + 6];
          f3 = sea[pos + 7];
          h0 = GAT(f0); h1 = GAT(f1); h2 = GAT(f2); h3 = GAT(f3);
        }
        edge_step2(g0, e0, we0, we1, we2, at6, xrl, num, den);
        edge_step2(g1, e1, we0, we1, we2, at6, xrl, num, den);
        edge_step2(g2, e2, we0, we1, we2, at6, xrl, num, den);
        edge_step2(g3, e3, we0, we1, we2, at6, xrl, num, den);
        g0 = h0; g1 = h1; g2 = h2; g3 = h3;
        e0 = f0; e1 = f1; e2 = f2; e3 = f3;
        pos += 4;
      }
      const int rem = end - pos;  // 0..3, half-uniform
      if (rem > 0) edge_step2(g0, e0, we0, we1, we2, at6, xrl, num, den);
      if (rem > 1) edge_step2(g1, e1, we0, we1, we2, at6, xrl, num, den);
      if (rem > 2) edge_step2(g2, e2, we0, we1, we2, at6, xrl, num, den);
    }

    // ---- finalize (all 64 lanes reconverged) ----
    const float inv = 1.f / (den + 1e-16f);
    float rr[8];
#pragma unroll
    for (int t = 0; t < 4; ++t) {
      rr[2 * t] = num[t].x * inv;
      rr[2 * t + 1] = num[t].y * inv;
    }
    // combine 4 heads: lanes {c, c+8, c+16, c+24} within each half hold the
    // same channels; xor 8 and xor 16 stay inside the 32-lane half.
#pragma unroll
    for (int t = 0; t < 8; ++t) {
      rr[t] += __shfl_xor(rr[t], 8);
      rr[t] += __shfl_xor(rr[t], 16);
    }
    if (hl < 8 && dv) {
      float o[8];
      o[0] = 0.25f * rr[0] + biasA.x;
      o[1] = 0.25f * rr[1] + biasA.y;
      o[2] = 0.25f * rr[2] + biasA.z;
      o[3] = 0.25f * rr[3] + biasA.w;
      o[4] = 0.25f * rr[4] + biasB.x;
      o[5] = 0.25f * rr[5] + biasB.y;
      o[6] = 0.25f * rr[6] + biasB.z;
      o[7] = 0.25f * rr[7] + biasB.w;
      if (MODE == 1) {
        const float pwv[8] = {pwA.x, pwA.y, pwA.z, pwA.w, pwB.x, pwB.y, pwB.z, pwB.w};
#pragma unroll
        for (int j = 0; j < 8; ++j) o[j] = (o[j] >= 0.f) ? o[j] : pwv[j] * o[j];
        float* op = out + (size_t)dd * 64 + hl * 8;
        *(float4*)op = make_float4(o[0], o[1], o[2], o[3]);
        *(float4*)(op + 4) = make_float4(o[4], o[5], o[6], o[7]);
      } else {
        u16x8 hb;
#pragma unroll
        for (int j = 0; j < 8; ++j) {
          __hip_bfloat16 h = __float2bfloat16(o[j]);
          hb[j] = *(ushort*)&h;
        }
        *(u16x8*)(outs + (size_t)dd * 64 + hl * 8) = hb;
      }
    }
  }
#undef GAT
}

extern "C" void kernel_launch(void* const* d_in, const int* in_sizes, int n_in,
                              void* d_out, int out_size, void* d_ws, size_t ws_size,
                              hipStream_t stream) {
  const float* x    = (const float*)d_in[0];
  const int*   ei   = (const int*)d_in[1];
  const float* ea   = (const float*)d_in[2];
  const float* Wl1  = (const float*)d_in[3];
  const float* Wr1  = (const float*)d_in[4];
  const float* We1  = (const float*)d_in[5];
  const float* att1 = (const float*)d_in[6];
  const float* b1   = (const float*)d_in[7];
  const float* Wl2  = (const float*)d_in[8];
  const float* Wr2  = (const float*)d_in[9];
  const float* We2  = (const float*)d_in[10];
  const float* att2 = (const float*)d_in[11];
  const float* b2   = (const float*)d_in[12];
  const float* pw   = (const float*)d_in[13];
  const int N_ = in_sizes[0] / 128;
  const int E_ = in_sizes[1] / 2;
  float* out = (float*)d_out;

  char* w = (char*)d_ws;
  auto alloc = [&](size_t bytes) {
    char* p = w;
    w += (bytes + 255) & ~size_t(255);
    return p;
  };
  ushort* xlb      = (ushort*)alloc((size_t)N_ * 256 * 2);   // bf16 gather operand
  ushort* xrb      = (ushort*)alloc((size_t)N_ * 256 * 2);   // bf16 logit operand
  ushort* Ax       = (ushort*)alloc((size_t)N_ * 128 * 2);   // bf16 cast of x
  ushort* h2       = (ushort*)alloc((size_t)N_ * 64 * 2);    // bf16 h (layer-2 A)
  float4* sea      = (float4*)alloc((size_t)(E_ + 8) * 16);  // {ea0,ea1,ea2,src}
  int*    deg      = (int*)alloc((size_t)N_ * 4);
  int*    rowstart = (int*)alloc((size_t)(N_ + 1) * 4);
  int*    cursor   = (int*)alloc((size_t)N_ * 4);
  int*    partial  = (int*)alloc(256 * 4);
  ushort* WT1      = (ushort*)alloc((size_t)512 * 128 * 2);
  ushort* WT2      = (ushort*)alloc((size_t)512 * 64 * 2);

  // ---- weight casts + histogram (deg zeroed via async memset) ----
  hipMemsetAsync(deg, 0, (size_t)N_ * 4, stream);
  const int wtot = 512 * 128 + 512 * 64 + E_;
  k_weights_hist<<<(wtot + 255) / 256, 256, 0, stream>>>(Wl1, Wr1, WT1, Wl2, Wr2, WT2,
                                                         ei, deg, E_);

  // ---- CSR build (2-kernel scan) + x cast + edge scatter ----
  const int nblk = (N_ + 255) / 256;
  k_scan_local<<<nblk, 256, 0, stream>>>(deg, rowstart, partial, N_);
  k_scan_final<<<nblk, 256, 0, stream>>>(partial, nblk, rowstart, cursor, sea, N_, E_);
  const int ptot = N_ * 16 + E_;
  k_prep<<<(ptot + 255) / 256, 256, 0, stream>>>(x, Ax, ei, ea, cursor, sea, N_, E_);

  const dim3 GG(4, (N_ + 127) / 128);  // x: col-blocks (xl,xl,xr,xr); y: rows
  const int chp = 2;                   // dst PAIRS per wave (4 dsts/wave)
  const int FB = (N_ + 2 * chp - 1) / (2 * chp);

  // ---- layer 1 ----
  gemm_mfma<128><<<GG, 256, 0, stream>>>(Ax, WT1, xlb, xrb, N_);
  fused_attn<0><<<FB, 64, 0, stream>>>(xlb, xrb, rowstart, sea, We1, att1,
                                       b1, pw, nullptr, h2, N_, chp);
  // ---- layer 2 ----
  gemm_mfma<64><<<GG, 256, 0, stream>>>(h2, WT2, xlb, xrb, N_);
  fused_attn<1><<<FB, 64, 0, stream>>>(xlb, xrb, rowstart, sea, We2, att2,
                                       b2, pw, out, nullptr, N_, chp);
}

// Round 6
// 280.586 us; speedup vs baseline: 1.2692x; 1.2692x over previous
//
#include <hip/hip_runtime.h>
#include <hip/hip_bf16.h>

#define HC 256

typedef __attribute__((ext_vector_type(8))) short bf16x8;
typedef __attribute__((ext_vector_type(8))) unsigned short u16x8;
typedef __attribute__((ext_vector_type(4))) float f32x4;
typedef __attribute__((ext_vector_type(2))) float f32x2;

__device__ __forceinline__ void gl_lds16(const void* g, void* l) {
  __builtin_amdgcn_global_load_lds(
      (const __attribute__((address_space(1))) unsigned int*)g,
      (__attribute__((address_space(3))) unsigned int*)l, 16, 0, 0);
}

// ==== bf16 weight casts (both layers) + dst-degree histogram, one kernel ===
__device__ __forceinline__ void cast_w_one(const float* Wl, const float* Wr,
                                           ushort* WT, int F, int idx) {
  int col = idx / F, f = idx - col * F;
  float v = (col < 256) ? Wl[col * F + f] : Wr[(col - 256) * F + f];
  __hip_bfloat16 h = __float2bfloat16(v);
  WT[(size_t)col * F + f] = *(ushort*)&h;
}

__global__ void k_weights_hist(const float* __restrict__ Wl1, const float* __restrict__ Wr1,
                               ushort* __restrict__ WT1, const float* __restrict__ Wl2,
                               const float* __restrict__ Wr2, ushort* __restrict__ WT2,
                               const int* __restrict__ ei, int* __restrict__ deg, int E_) {
  int idx = blockIdx.x * blockDim.x + threadIdx.x;
  const int t1 = 512 * 128, t2 = 512 * 64;
  if (idx < t1) {
    cast_w_one(Wl1, Wr1, WT1, 128, idx);
  } else if (idx < t1 + t2) {
    cast_w_one(Wl2, Wr2, WT2, 64, idx - t1);
  } else {
    int e = idx - t1 - t2;
    if (e < E_) atomicAdd(&deg[ei[E_ + e]], 1);
  }
}

// ======== MFMA GEMM: K-pipelined, disjoint LDS buffers per K-step ==========
// 4 waves, 128x128 block tile, 64x64 wave tile, BK=64.
template <int F>
__global__ __launch_bounds__(256) void gemm_mfma(const ushort* __restrict__ A,
                                                 const ushort* __restrict__ WT,
                                                 ushort* __restrict__ xlb,
                                                 ushort* __restrict__ xrb, int n_nodes) {
  constexpr int NSTEP = F / 64;
  constexpr int SM = (2 * NSTEP * 8192 > 17408) ? 2 * NSTEP * 8192 : 17408;
  __shared__ __align__(16) ushort smem[SM];
  const int tid = threadIdx.x;
  const int wv = tid >> 6, lane = tid & 63;
  const int m16 = lane & 15, quad = lane >> 4;
  const int col0 = blockIdx.x * 128;  // 0,1 -> xl ; 2,3 -> xr
  const int row0 = blockIdx.y * 128;
  const int wm = (wv >> 1) * 64, wn = (wv & 1) * 64;

  f32x4 acc[4][4];
#pragma unroll
  for (int i = 0; i < 4; ++i)
#pragma unroll
    for (int j = 0; j < 4; ++j) acc[i][j] = (f32x4){0.f, 0.f, 0.f, 0.f};

  auto load_step = [&](int s) {
    ushort* As = smem + s * 16384;
    ushort* Bs = As + 8192;
    const int khat = s * 64;
#pragma unroll
    for (int t = 0; t < 4; ++t) {
      const int sl16 = tid + 256 * t;  // LDS slot (16B units), linear in lane
      const int row = sl16 >> 3, sl = sl16 & 7;
      const int gch = sl ^ (row & 7);  // swizzle on the GLOBAL address
      const int grow = row0 + row;
      if (grow < n_nodes)
        gl_lds16(A + (size_t)grow * F + khat + gch * 8, As + sl16 * 8);
      gl_lds16(WT + (size_t)(col0 + row) * F + khat + gch * 8, Bs + sl16 * 8);
    }
  };

  auto mfma_step = [&](int s) {
    ushort* As = smem + s * 16384;
    ushort* Bs = As + 8192;
#pragma unroll
    for (int kh = 0; kh < 2; ++kh) {
      bf16x8 af[4], bf[4];
#pragma unroll
      for (int i = 0; i < 4; ++i) {
        const int row = wm + i * 16 + m16;
        const int slot = (kh * 4 + quad) ^ (row & 7);
        af[i] = *(bf16x8*)&As[row * 64 + slot * 8];
      }
#pragma unroll
      for (int j = 0; j < 4; ++j) {
        const int col = wn + j * 16 + m16;
        const int slot = (kh * 4 + quad) ^ (col & 7);
        bf[j] = *(bf16x8*)&Bs[col * 64 + slot * 8];
      }
#pragma unroll
      for (int i = 0; i < 4; ++i)
#pragma unroll
        for (int j = 0; j < 4; ++j)
          acc[i][j] =
              __builtin_amdgcn_mfma_f32_16x16x32_bf16(af[i], bf[j], acc[i][j], 0, 0, 0);
    }
  };

  load_step(0);
  __syncthreads();
  if (NSTEP > 1) load_step(1);  // DMAs overlap mfma_step(0)
  mfma_step(0);
  if (NSTEP > 1) {
    __syncthreads();  // drains step-1 loads (had mfma(0) time to land)
    mfma_step(1);
  }

  // ---- epilogue: acc -> bf16 -> LDS (pitch 136) -> coalesced 16B stores ----
  __syncthreads();  // all LDS reads done; safe to alias with Ct
  ushort* Ct = smem;
#pragma unroll
  for (int i = 0; i < 4; ++i) {
#pragma unroll
    for (int r = 0; r < 4; ++r) {
      const int row = wm + i * 16 + quad * 4 + r;
#pragma unroll
      for (int j = 0; j < 4; ++j) {
        __hip_bfloat16 h = __float2bfloat16(acc[i][j][r]);
        Ct[row * 136 + wn + j * 16 + m16] = *(ushort*)&h;
      }
    }
  }
  __syncthreads();
  const bool is_xl = (col0 < 256);
  ushort* dst = is_xl ? xlb : xrb;
  const int cb = is_xl ? col0 : (col0 - 256);
  const int chunk = tid & 15;  // 16B chunk within the 256B row
#pragma unroll
  for (int it = 0; it < 8; ++it) {
    const int row = (tid >> 4) + 16 * it;
    const int grow = row0 + row;
    int4 v = *(int4*)&Ct[row * 136 + chunk * 8];
    if (grow < n_nodes)
      *(int4*)(dst + (size_t)grow * 256 + cb + chunk * 8) = v;
  }
}

// ================= CSR build (edges bucketed by dst) =======================
__global__ void k_scan_local(const int* __restrict__ deg, int* __restrict__ rowstart,
                             int* __restrict__ partial, int n) {
  __shared__ int a[256], b[256];
  const int t = threadIdx.x;
  const int i = blockIdx.x * 256 + t;
  const int v = (i < n) ? deg[i] : 0;
  a[t] = v;
  __syncthreads();
  int* cur = a;
  int* nxt = b;
  for (int off = 1; off < 256; off <<= 1) {
    int x = cur[t];
    if (t >= off) x += cur[t - off];
    nxt[t] = x;
    __syncthreads();
    int* tmp = cur; cur = nxt; nxt = tmp;
  }
  const int incl = cur[t];
  if (i < n) rowstart[i] = incl - v;
  if (t == 255) partial[blockIdx.x] = incl;
}

// merged: every block redundantly scans the block-sums (nblk<=256), adds its
// exclusive prefix, writes rowstart+cursor; block 0 zero-fills the CSR pad.
__global__ void k_scan_final(const int* __restrict__ partial, int nblk,
                             int* __restrict__ rowstart, int* __restrict__ cursor,
                             float4* __restrict__ sea, int n, int E_) {
  __shared__ int a[256], b[256];
  const int t = threadIdx.x;
  const int v = (t < nblk) ? partial[t] : 0;
  a[t] = v;
  __syncthreads();
  int* cur = a;
  int* nxt = b;
  for (int off = 1; off < 256; off <<= 1) {
    int x = cur[t];
    if (t >= off) x += cur[t - off];
    nxt[t] = x;
    __syncthreads();
    int* tmp = cur; cur = nxt; nxt = tmp;
  }
  const int boff = (blockIdx.x > 0) ? cur[blockIdx.x - 1] : 0;
  const int i = blockIdx.x * 256 + t;
  if (i < n) {
    int vv = rowstart[i] + boff;
    rowstart[i] = vv;
    cursor[i] = vv;
  }
  if (i == 0) rowstart[n] = E_;
  if (blockIdx.x == 0 && t < 8) sea[E_ + t] = make_float4(0.f, 0.f, 0.f, 0.f);
}

// ==== fused: cast x -> bf16 A AND CSR edge scatter (src packed in sea.w) ===
__global__ void k_prep(const float* __restrict__ x, ushort* __restrict__ A,
                       const int* __restrict__ ei, const float* __restrict__ ea,
                       int* __restrict__ cursor, float4* __restrict__ sea,
                       int n, int E_) {
  const int nx8 = n * 16;  // 8 elements per thread
  int idx = blockIdx.x * blockDim.x + threadIdx.x;
  if (idx < nx8) {
    const float4* xp = (const float4*)x + (size_t)idx * 2;
    float4 v0 = xp[0], v1 = xp[1];
    float vv[8] = {v0.x, v0.y, v0.z, v0.w, v1.x, v1.y, v1.z, v1.w};
    __align__(16) ushort hb[8];
#pragma unroll
    for (int j = 0; j < 8; ++j) {
      __hip_bfloat16 h = __float2bfloat16(vv[j]);
      hb[j] = *(ushort*)&h;
    }
    *(int4*)(A + (size_t)idx * 8) = *(int4*)hb;
  } else {
    int e = idx - nx8;
    if (e < E_) {
      int dst = ei[E_ + e];
      int pos = atomicAdd(&cursor[dst], 1);
      sea[pos] = make_float4(ea[e * 3], ea[e * 3 + 1], ea[e * 3 + 2],
                             __int_as_float(ei[e]));
    }
  }
}

// ================= fused per-destination attention =========================
// ONE wave per workgroup; HALF-WAVE DST PAIRING: lanes 0-31 process dst d,
// lanes 32-63 process dst d+1 (independent gather streams; every VALU inst
// covers 2 edges). Each lane holds 8 channels (ushort8 = 16B gathers,
// 8 lanes/head). Pipeline depth 2 PAIRS (4 edges wave-wide in flight, same
// memory parallelism as the R4 kernel, half the register state — R5's
// depth-4 + tight launch_bounds spilled to scratch: WRITE_SIZE 12.5->148MB).
// 8-lane head reduce via DPP. Logit: att·lrelu(s) = 0.6·att·(s+(2/3)|s|),
// at6 pre-scaled by log2(e) so w = exp2(p).
__device__ __forceinline__ float dpp_add8(float p) {
  p += __int_as_float(__builtin_amdgcn_update_dpp(
      0, __float_as_int(p), 0xB1, 0xF, 0xF, true));   // quad_perm [1,0,3,2] = xor1
  p += __int_as_float(__builtin_amdgcn_update_dpp(
      0, __float_as_int(p), 0x4E, 0xF, 0xF, true));   // quad_perm [2,3,0,1] = xor2
  p += __int_as_float(__builtin_amdgcn_update_dpp(
      0, __float_as_int(p), 0x141, 0xF, 0xF, true));  // row_half_mirror (8-lane)
  return p;
}

__device__ __forceinline__ void expand8(const u16x8& v, f32x2* o) {
#pragma unroll
  for (int t = 0; t < 4; ++t) {
    o[t].x = __uint_as_float((unsigned)v[2 * t] << 16);
    o[t].y = __uint_as_float((unsigned)v[2 * t + 1] << 16);
  }
}

__device__ __forceinline__ void edge_step2(
    const u16x8& lu, const float4& eav, const f32x2* we0, const f32x2* we1,
    const f32x2* we2, const f32x2* at6, const f32x2* xrl,
    f32x2* num, float& den) {
  f32x2 la[4];
  expand8(lu, la);
  f32x2 pv = {0.f, 0.f};
#pragma unroll
  for (int j = 0; j < 4; ++j) {
    f32x2 t = xrl[j] + we0[j] * eav.x;  // fma chain rooted at xr
    t = t + we1[j] * eav.y;
    t = t + we2[j] * eav.z;
    f32x2 s = t + la[j];
    f32x2 u;
    u.x = fmaf(fabsf(s.x), 0.66666667f, s.x);  // s + (2/3)|s|; abs is free
    u.y = fmaf(fabsf(s.y), 0.66666667f, s.y);
    pv = pv + at6[j] * u;
  }
  float p = pv.x + pv.y;
  p = dpp_add8(p);           // sum over the 8-lane head group
  const float w = exp2f(p);  // at6 carries 0.6*log2(e); |logit| small
  den += w;
#pragma unroll
  for (int j = 0; j < 4; ++j) num[j] = num[j] + (f32x2){w, w} * la[j];
}

template <int MODE>
__global__ __launch_bounds__(64, 2) void fused_attn(
    const ushort* __restrict__ xlb, const ushort* __restrict__ xrb,
    const int* __restrict__ rowstart, const float4* __restrict__ sea,
    const float* __restrict__ We, const float* __restrict__ att,
    const float* __restrict__ bias, const float* __restrict__ pw,
    float* __restrict__ out, ushort* __restrict__ outs, int n, int chp) {
  const int lane = threadIdx.x;
  const int half = lane >> 5;   // 0: even dst, 1: odd dst
  const int hl = lane & 31;     // lane within half; channels r = 8*hl + j
  const int d0 = blockIdx.x * (2 * chp);
  if (d0 >= n) return;

  // ---- prologue: per-lane weights for 8 channels (vector loads) ----
  float wf[24];
  {
    const float4* Wq = (const float4*)We + 6 * hl;  // rows 8hl..8hl+7, 3 floats each
#pragma unroll
    for (int t = 0; t < 6; ++t) *(float4*)&wf[4 * t] = Wq[t];
  }
  float af[8];
  {
    const float4* Aq = (const float4*)att + 2 * hl;
    *(float4*)&af[0] = Aq[0];
    *(float4*)&af[4] = Aq[1];
  }
  f32x2 we0[4], we1[4], we2[4], at6[4];
  const float C6 = 0.6f * 1.4426950408889634f;
#pragma unroll
  for (int j = 0; j < 8; ++j) {
    ((float*)we0)[j] = wf[3 * j + 0];
    ((float*)we1)[j] = wf[3 * j + 1];
    ((float*)we2)[j] = wf[3 * j + 2];
    ((float*)at6)[j] = af[j] * C6;
  }
  const int cb8 = 8 * (hl & 7);  // channel base for the store lanes (hl<8)
  const float4 biasA = *(const float4*)&bias[cb8];
  const float4 biasB = *(const float4*)&bias[cb8 + 4];
  float4 pwA = {0.f, 0.f, 0.f, 0.f}, pwB = {0.f, 0.f, 0.f, 0.f};
  if (MODE == 1) {
    pwA = *(const float4*)&pw[cb8];
    pwB = *(const float4*)&pw[cb8 + 4];
  }

#define GAT(e_) (*(const u16x8*)&xlb[(size_t)(unsigned)__float_as_int((e_).w) * 256 + hl * 8])

  for (int k = 0; k < chp; ++k) {
    const int dd = d0 + 2 * k + half;  // per-half dst
    const bool dv = dd < n;
    const int dc = dv ? dd : n - 1;    // clamp for safe loads

    u16x8 xu = *(const u16x8*)&xrb[(size_t)dc * 256 + hl * 8];
    f32x2 xrl[4];
    expand8(xu, xrl);

    int pos = rowstart[dc];
    const int end = dv ? rowstart[dc + 1] : pos;
    f32x2 num[4] = {{0.f, 0.f}, {0.f, 0.f}, {0.f, 0.f}, {0.f, 0.f}};
    float den = 0.f;

    if (pos < end) {  // half-uniform; exhausted half is exec-masked off
      // CSR padded by 8 zero entries past E: over-read safe. src in sea.w.
      float4 e0 = sea[pos], e1 = sea[pos + 1];
      u16x8 g0 = GAT(e0), g1 = GAT(e1);

      while (pos + 2 <= end) {
        u16x8 h0 = g0, h1 = g1;
        float4 f0 = e0, f1 = e1;
        if (pos + 2 < end) {  // half-uniform: prefetch only if more edges
          f0 = sea[pos + 2];
          f1 = sea[pos + 3];
          h0 = GAT(f0);
          h1 = GAT(f1);
        }
        edge_step2(g0, e0, we0, we1, we2, at6, xrl, num, den);
        edge_step2(g1, e1, we0, we1, we2, at6, xrl, num, den);
        g0 = h0; g1 = h1;
        e0 = f0; e1 = f1;
        pos += 2;
      }
      if (end - pos > 0)  // remainder: 0 or 1, half-uniform
        edge_step2(g0, e0, we0, we1, we2, at6, xrl, num, den);
    }

    // ---- finalize (all 64 lanes reconverged) ----
    const float inv = 1.f / (den + 1e-16f);
    float rr[8];
#pragma unroll
    for (int t = 0; t < 4; ++t) {
      rr[2 * t] = num[t].x * inv;
      rr[2 * t + 1] = num[t].y * inv;
    }
    // combine 4 heads: lanes {c, c+8, c+16, c+24} within each half hold the
    // same channels; xor 8 and xor 16 stay inside the 32-lane half.
#pragma unroll
    for (int t = 0; t < 8; ++t) {
      rr[t] += __shfl_xor(rr[t], 8);
      rr[t] += __shfl_xor(rr[t], 16);
    }
    if (hl < 8 && dv) {
      float o[8];
      o[0] = 0.25f * rr[0] + biasA.x;
      o[1] = 0.25f * rr[1] + biasA.y;
      o[2] = 0.25f * rr[2] + biasA.z;
      o[3] = 0.25f * rr[3] + biasA.w;
      o[4] = 0.25f * rr[4] + biasB.x;
      o[5] = 0.25f * rr[5] + biasB.y;
      o[6] = 0.25f * rr[6] + biasB.z;
      o[7] = 0.25f * rr[7] + biasB.w;
      if (MODE == 1) {
        const float pwv[8] = {pwA.x, pwA.y, pwA.z, pwA.w, pwB.x, pwB.y, pwB.z, pwB.w};
#pragma unroll
        for (int j = 0; j < 8; ++j) o[j] = (o[j] >= 0.f) ? o[j] : pwv[j] * o[j];
        float* op = out + (size_t)dd * 64 + hl * 8;
        *(float4*)op = make_float4(o[0], o[1], o[2], o[3]);
        *(float4*)(op + 4) = make_float4(o[4], o[5], o[6], o[7]);
      } else {
        u16x8 hb;
#pragma unroll
        for (int j = 0; j < 8; ++j) {
          __hip_bfloat16 h = __float2bfloat16(o[j]);
          hb[j] = *(ushort*)&h;
        }
        *(u16x8*)(outs + (size_t)dd * 64 + hl * 8) = hb;
      }
    }
  }
#undef GAT
}

extern "C" void kernel_launch(void* const* d_in, const int* in_sizes, int n_in,
                              void* d_out, int out_size, void* d_ws, size_t ws_size,
                              hipStream_t stream) {
  const float* x    = (const float*)d_in[0];
  const int*   ei   = (const int*)d_in[1];
  const float* ea   = (const float*)d_in[2];
  const float* Wl1  = (const float*)d_in[3];
  const float* Wr1  = (const float*)d_in[4];
  const float* We1  = (const float*)d_in[5];
  const float* att1 = (const float*)d_in[6];
  const float* b1   = (const float*)d_in[7];
  const float* Wl2  = (const float*)d_in[8];
  const float* Wr2  = (const float*)d_in[9];
  const float* We2  = (const float*)d_in[10];
  const float* att2 = (const float*)d_in[11];
  const float* b2   = (const float*)d_in[12];
  const float* pw   = (const float*)d_in[13];
  const int N_ = in_sizes[0] / 128;
  const int E_ = in_sizes[1] / 2;
  float* out = (float*)d_out;

  char* w = (char*)d_ws;
  auto alloc = [&](size_t bytes) {
    char* p = w;
    w += (bytes + 255) & ~size_t(255);
    return p;
  };
  ushort* xlb      = (ushort*)alloc((size_t)N_ * 256 * 2);   // bf16 gather operand
  ushort* xrb      = (ushort*)alloc((size_t)N_ * 256 * 2);   // bf16 logit operand
  ushort* Ax       = (ushort*)alloc((size_t)N_ * 128 * 2);   // bf16 cast of x
  ushort* h2       = (ushort*)alloc((size_t)N_ * 64 * 2);    // bf16 h (layer-2 A)
  float4* sea      = (float4*)alloc((size_t)(E_ + 8) * 16);  // {ea0,ea1,ea2,src}
  int*    deg      = (int*)alloc((size_t)N_ * 4);
  int*    rowstart = (int*)alloc((size_t)(N_ + 1) * 4);
  int*    cursor   = (int*)alloc((size_t)N_ * 4);
  int*    partial  = (int*)alloc(256 * 4);
  ushort* WT1      = (ushort*)alloc((size_t)512 * 128 * 2);
  ushort* WT2      = (ushort*)alloc((size_t)512 * 64 * 2);

  // ---- weight casts + histogram (deg zeroed via async memset) ----
  hipMemsetAsync(deg, 0, (size_t)N_ * 4, stream);
  const int wtot = 512 * 128 + 512 * 64 + E_;
  k_weights_hist<<<(wtot + 255) / 256, 256, 0, stream>>>(Wl1, Wr1, WT1, Wl2, Wr2, WT2,
                                                         ei, deg, E_);

  // ---- CSR build (2-kernel scan) + x cast + edge scatter ----
  const int nblk = (N_ + 255) / 256;
  k_scan_local<<<nblk, 256, 0, stream>>>(deg, rowstart, partial, N_);
  k_scan_final<<<nblk, 256, 0, stream>>>(partial, nblk, rowstart, cursor, sea, N_, E_);
  const int ptot = N_ * 16 + E_;
  k_prep<<<(ptot + 255) / 256, 256, 0, stream>>>(x, Ax, ei, ea, cursor, sea, N_, E_);

  const dim3 GG(4, (N_ + 127) / 128);  // x: col-blocks (xl,xl,xr,xr); y: rows
  const int chp = 2;                   // dst PAIRS per wave (4 dsts/wave)
  const int FB = (N_ + 2 * chp - 1) / (2 * chp);

  // ---- layer 1 ----
  gemm_mfma<128><<<GG, 256, 0, stream>>>(Ax, WT1, xlb, xrb, N_);
  fused_attn<0><<<FB, 64, 0, stream>>>(xlb, xrb, rowstart, sea, We1, att1,
                                       b1, pw, nullptr, h2, N_, chp);
  // ---- layer 2 ----
  gemm_mfma<64><<<GG, 256, 0, stream>>>(h2, WT2, xlb, xrb, N_);
  fused_attn<1><<<FB, 64, 0, stream>>>(xlb, xrb, rowstart, sea, We2, att2,
                                       b2, pw, out, nullptr, N_, chp);
}

// Round 7
// 261.347 us; speedup vs baseline: 1.3627x; 1.0736x over previous
//
#include <hip/hip_runtime.h>
#include <hip/hip_bf16.h>

#define HC 256

typedef __attribute__((ext_vector_type(8))) short bf16x8;
typedef __attribute__((ext_vector_type(4))) float f32x4;
typedef __attribute__((ext_vector_type(2))) float f32x2;

__device__ __forceinline__ void gl_lds16(const void* g, void* l) {
  __builtin_amdgcn_global_load_lds(
      (const __attribute__((address_space(1))) unsigned int*)g,
      (__attribute__((address_space(3))) unsigned int*)l, 16, 0, 0);
}

// ==== bf16 weight casts (both layers) + dst-degree histogram, one kernel ===
__device__ __forceinline__ void cast_w_one(const float* Wl, const float* Wr,
                                           ushort* WT, int F, int idx) {
  int col = idx / F, f = idx - col * F;
  float v = (col < 256) ? Wl[col * F + f] : Wr[(col - 256) * F + f];
  __hip_bfloat16 h = __float2bfloat16(v);
  WT[(size_t)col * F + f] = *(ushort*)&h;
}

__global__ void k_weights_hist(const float* __restrict__ Wl1, const float* __restrict__ Wr1,
                               ushort* __restrict__ WT1, const float* __restrict__ Wl2,
                               const float* __restrict__ Wr2, ushort* __restrict__ WT2,
                               const int* __restrict__ ei, int* __restrict__ deg, int E_) {
  int idx = blockIdx.x * blockDim.x + threadIdx.x;
  const int t1 = 512 * 128, t2 = 512 * 64;
  if (idx < t1) {
    cast_w_one(Wl1, Wr1, WT1, 128, idx);
  } else if (idx < t1 + t2) {
    cast_w_one(Wl2, Wr2, WT2, 64, idx - t1);
  } else {
    int e = idx - t1 - t2;
    if (e < E_) atomicAdd(&deg[ei[E_ + e]], 1);
  }
}

// ======== MFMA GEMM: single 32KB stage buffer, sequential K-steps ==========
// 4 waves, 128x128 block tile, 64x64 wave tile, BK=64.
// LDS = max(stage 32KB, epilogue 34.8KB) = 34.8KB -> 4 blocks/CU (vs 2 at
// the old 64KB disjoint-dbuf). Inter-block wave overlap replaces the lost
// intra-block DMA/MFMA overlap (m114/m132 evidence: occupancy wins).
template <int F>
__global__ __launch_bounds__(256) void gemm_mfma(const ushort* __restrict__ A,
                                                 const ushort* __restrict__ WT,
                                                 ushort* __restrict__ xlb,
                                                 ushort* __restrict__ xrb, int n_nodes) {
  constexpr int NSTEP = F / 64;
  constexpr int SM = 17408;  // epilogue Ct (128 x pitch136) > stage 16384
  __shared__ __align__(16) ushort smem[SM];
  const int tid = threadIdx.x;
  const int wv = tid >> 6, lane = tid & 63;
  const int m16 = lane & 15, quad = lane >> 4;
  const int col0 = blockIdx.x * 128;  // 0,1 -> xl ; 2,3 -> xr
  const int row0 = blockIdx.y * 128;
  const int wm = (wv >> 1) * 64, wn = (wv & 1) * 64;

  f32x4 acc[4][4];
#pragma unroll
  for (int i = 0; i < 4; ++i)
#pragma unroll
    for (int j = 0; j < 4; ++j) acc[i][j] = (f32x4){0.f, 0.f, 0.f, 0.f};

  ushort* As = smem;
  ushort* Bs = smem + 8192;

  auto load_step = [&](int s) {
    const int khat = s * 64;
#pragma unroll
    for (int t = 0; t < 4; ++t) {
      const int sl16 = tid + 256 * t;  // LDS slot (16B units), linear in lane
      const int row = sl16 >> 3, sl = sl16 & 7;
      const int gch = sl ^ (row & 7);  // swizzle on the GLOBAL address
      const int grow = row0 + row;
      if (grow < n_nodes)
        gl_lds16(A + (size_t)grow * F + khat + gch * 8, As + sl16 * 8);
      gl_lds16(WT + (size_t)(col0 + row) * F + khat + gch * 8, Bs + sl16 * 8);
    }
  };

  auto mfma_step = [&]() {
#pragma unroll
    for (int kh = 0; kh < 2; ++kh) {
      bf16x8 af[4], bf[4];
#pragma unroll
      for (int i = 0; i < 4; ++i) {
        const int row = wm + i * 16 + m16;
        const int slot = (kh * 4 + quad) ^ (row & 7);
        af[i] = *(bf16x8*)&As[row * 64 + slot * 8];
      }
#pragma unroll
      for (int j = 0; j < 4; ++j) {
        const int col = wn + j * 16 + m16;
        const int slot = (kh * 4 + quad) ^ (col & 7);
        bf[j] = *(bf16x8*)&Bs[col * 64 + slot * 8];
      }
#pragma unroll
      for (int i = 0; i < 4; ++i)
#pragma unroll
        for (int j = 0; j < 4; ++j)
          acc[i][j] =
              __builtin_amdgcn_mfma_f32_16x16x32_bf16(af[i], bf[j], acc[i][j], 0, 0, 0);
    }
  };

  load_step(0);
  __syncthreads();
  mfma_step();
  if (NSTEP > 1) {
    __syncthreads();  // all LDS reads of step 0 done before overwrite
    load_step(1);
    __syncthreads();  // drains step-1 DMAs
    mfma_step();
  }

  // ---- epilogue: acc -> bf16 -> LDS (pitch 136) -> coalesced 16B stores ----
  __syncthreads();  // all LDS reads done; safe to alias with Ct
  ushort* Ct = smem;
#pragma unroll
  for (int i = 0; i < 4; ++i) {
#pragma unroll
    for (int r = 0; r < 4; ++r) {
      const int row = wm + i * 16 + quad * 4 + r;
#pragma unroll
      for (int j = 0; j < 4; ++j) {
        __hip_bfloat16 h = __float2bfloat16(acc[i][j][r]);
        Ct[row * 136 + wn + j * 16 + m16] = *(ushort*)&h;
      }
    }
  }
  __syncthreads();
  const bool is_xl = (col0 < 256);
  ushort* dst = is_xl ? xlb : xrb;
  const int cb = is_xl ? col0 : (col0 - 256);
  const int chunk = tid & 15;  // 16B chunk within the 256B row
#pragma unroll
  for (int it = 0; it < 8; ++it) {
    const int row = (tid >> 4) + 16 * it;
    const int grow = row0 + row;
    int4 v = *(int4*)&Ct[row * 136 + chunk * 8];
    if (grow < n_nodes)
      *(int4*)(dst + (size_t)grow * 256 + cb + chunk * 8) = v;
  }
}

// ================= CSR build (edges bucketed by dst) =======================
__global__ void k_scan_local(const int* __restrict__ deg, int* __restrict__ rowstart,
                             int* __restrict__ partial, int n) {
  __shared__ int a[256], b[256];
  const int t = threadIdx.x;
  const int i = blockIdx.x * 256 + t;
  const int v = (i < n) ? deg[i] : 0;
  a[t] = v;
  __syncthreads();
  int* cur = a;
  int* nxt = b;
  for (int off = 1; off < 256; off <<= 1) {
    int x = cur[t];
    if (t >= off) x += cur[t - off];
    nxt[t] = x;
    __syncthreads();
    int* tmp = cur; cur = nxt; nxt = tmp;
  }
  const int incl = cur[t];
  if (i < n) rowstart[i] = incl - v;
  if (t == 255) partial[blockIdx.x] = incl;
}

// merged: every block redundantly scans the block-sums (nblk<=256), adds its
// exclusive prefix, writes rowstart+cursor; block 0 zero-fills the CSR pad.
__global__ void k_scan_final(const int* __restrict__ partial, int nblk,
                             int* __restrict__ rowstart, int* __restrict__ cursor,
                             float4* __restrict__ sea, int n, int E_) {
  __shared__ int a[256], b[256];
  const int t = threadIdx.x;
  const int v = (t < nblk) ? partial[t] : 0;
  a[t] = v;
  __syncthreads();
  int* cur = a;
  int* nxt = b;
  for (int off = 1; off < 256; off <<= 1) {
    int x = cur[t];
    if (t >= off) x += cur[t - off];
    nxt[t] = x;
    __syncthreads();
    int* tmp = cur; cur = nxt; nxt = tmp;
  }
  const int boff = (blockIdx.x > 0) ? cur[blockIdx.x - 1] : 0;
  const int i = blockIdx.x * 256 + t;
  if (i < n) {
    int vv = rowstart[i] + boff;
    rowstart[i] = vv;
    cursor[i] = vv;
  }
  if (i == 0) rowstart[n] = E_;
  if (blockIdx.x == 0 && t < 8) sea[E_ + t] = make_float4(0.f, 0.f, 0.f, 0.f);
}

// ==== fused: cast x -> bf16 A AND CSR edge scatter (src packed in sea.w) ===
__global__ void k_prep(const float* __restrict__ x, ushort* __restrict__ A,
                       const int* __restrict__ ei, const float* __restrict__ ea,
                       int* __restrict__ cursor, float4* __restrict__ sea,
                       int n, int E_) {
  const int nx8 = n * 16;  // 8 elements per thread
  int idx = blockIdx.x * blockDim.x + threadIdx.x;
  if (idx < nx8) {
    const float4* xp = (const float4*)x + (size_t)idx * 2;
    float4 v0 = xp[0], v1 = xp[1];
    float vv[8] = {v0.x, v0.y, v0.z, v0.w, v1.x, v1.y, v1.z, v1.w};
    __align__(16) ushort hb[8];
#pragma unroll
    for (int j = 0; j < 8; ++j) {
      __hip_bfloat16 h = __float2bfloat16(vv[j]);
      hb[j] = *(ushort*)&h;
    }
    *(int4*)(A + (size_t)idx * 8) = *(int4*)hb;
  } else {
    int e = idx - nx8;
    if (e < E_) {
      int dst = ei[E_ + e];
      int pos = atomicAdd(&cursor[dst], 1);
      sea[pos] = make_float4(ea[e * 3], ea[e * 3 + 1], ea[e * 3 + 2],
                             __int_as_float(ei[e]));
    }
  }
}

// ================= fused per-destination attention =========================
// ONE wave per workgroup; chunk dsts per wave; 4-edge software pipeline; src
// index packed in sea.w. MODE 0: bf16 h out. MODE 1: fp32 + PReLU.
// Logit: att·lrelu(s) = 0.6att·s + 0.4att·|s| (abs = free VOP3 modifier),
// at6/at4 pre-scaled by log2(e) so w = exp2(p). 16-lane reduce via DPP
// row_ror adds (pure VALU) instead of 4 dependent ds_swizzles.
__device__ __forceinline__ float dpp_ror_add(float p) {
  p += __int_as_float(__builtin_amdgcn_update_dpp(
      0, __float_as_int(p), 0x128, 0xF, 0xF, true));  // row_ror:8
  p += __int_as_float(__builtin_amdgcn_update_dpp(
      0, __float_as_int(p), 0x124, 0xF, 0xF, true));  // row_ror:4
  p += __int_as_float(__builtin_amdgcn_update_dpp(
      0, __float_as_int(p), 0x122, 0xF, 0xF, true));  // row_ror:2
  p += __int_as_float(__builtin_amdgcn_update_dpp(
      0, __float_as_int(p), 0x121, 0xF, 0xF, true));  // row_ror:1
  return p;
}

__device__ __forceinline__ void edge_step(
    const ushort4& lu, const float4& eav, const f32x2* we0, const f32x2* we1,
    const f32x2* we2, const f32x2* at6, const f32x2* at4, const f32x2* xrl,
    f32x2& num01, f32x2& num23, float& den) {
  f32x2 lav0, lav1;
  lav0.x = __uint_as_float((unsigned)lu.x << 16);
  lav0.y = __uint_as_float((unsigned)lu.y << 16);
  lav1.x = __uint_as_float((unsigned)lu.z << 16);
  lav1.y = __uint_as_float((unsigned)lu.w << 16);
  f32x2 pv = {0.f, 0.f};
#pragma unroll
  for (int j = 0; j < 2; ++j) {
    f32x2 la = (j == 0) ? lav0 : lav1;
    f32x2 t = xrl[j] + we0[j] * eav.x;   // fma chain rooted at xr (folds adds)
    t = t + we1[j] * eav.y;
    t = t + we2[j] * eav.z;
    f32x2 s = t + la;
    f32x2 sa = {fabsf(s.x), fabsf(s.y)}; // |s|: VOP3 input modifier, free
    pv = pv + at6[j] * s;
    pv = pv + at4[j] * sa;
  }
  float p = pv.x + pv.y;
  p = dpp_ror_add(p);          // sum over the 16-lane head group
  const float w = exp2f(p);    // at6/at4 carry log2(e); |logit| small
  den += w;
  num01 = num01 + (f32x2){w, w} * lav0;
  num23 = num23 + (f32x2){w, w} * lav1;
}

template <int MODE>
__global__ __launch_bounds__(64) void fused_attn(
    const ushort* __restrict__ xlb, const ushort* __restrict__ xrb,
    const int* __restrict__ rowstart, const float4* __restrict__ sea,
    const float* __restrict__ We, const float* __restrict__ att,
    const float* __restrict__ bias, const float* __restrict__ pw,
    float* __restrict__ out, ushort* __restrict__ outs, int n, int chunk) {
  const int lane = threadIdx.x;
  const int d0 = blockIdx.x * chunk;
  if (d0 >= n) return;
  const int d1 = min(d0 + chunk, n);

  // ---- prologue (amortized over the chunk) ----
  f32x2 we0[2], we1[2], we2[2], at6[2], at4[2];
  const float L2E = 1.4426950408889634f;
#pragma unroll
  for (int j = 0; j < 4; ++j) {
    int r = 4 * lane + j;
    ((float*)we0)[j] = We[r * 3 + 0];
    ((float*)we1)[j] = We[r * 3 + 1];
    ((float*)we2)[j] = We[r * 3 + 2];
    float a = att[r];
    ((float*)at6)[j] = a * (0.6f * L2E);
    ((float*)at4)[j] = a * (0.4f * L2E);
  }
  const float4 bias4 = ((const float4*)bias)[lane & 15];
  float4 pw4 = {0.f, 0.f, 0.f, 0.f};
  if (MODE == 1) pw4 = ((const float4*)pw)[lane & 15];
  const ushort4* xlb4 = (const ushort4*)xlb;

  for (int d = d0; d < d1; ++d) {
    const ushort4 xu = ((const ushort4*)xrb)[(unsigned)(d * 64) + lane];
    f32x2 xrl[2];
    xrl[0].x = __uint_as_float((unsigned)xu.x << 16);
    xrl[0].y = __uint_as_float((unsigned)xu.y << 16);
    xrl[1].x = __uint_as_float((unsigned)xu.z << 16);
    xrl[1].y = __uint_as_float((unsigned)xu.w << 16);

    int pos = rowstart[d];
    const int end = rowstart[d + 1];
    f32x2 num01 = {0.f, 0.f}, num23 = {0.f, 0.f};
    float den = 0.f;

    if (pos < end) {
      // CSR padded by 8 zero entries past E: over-read safe; pad/next-dst
      // entries are fetched but never processed. src index rides in sea.w.
      float4 e0 = sea[pos], e1 = sea[pos + 1], e2 = sea[pos + 2], e3 = sea[pos + 3];
      ushort4 g0 = xlb4[(unsigned)(__float_as_int(e0.w) * 64) + lane];
      ushort4 g1 = xlb4[(unsigned)(__float_as_int(e1.w) * 64) + lane];
      ushort4 g2 = xlb4[(unsigned)(__float_as_int(e2.w) * 64) + lane];
      ushort4 g3 = xlb4[(unsigned)(__float_as_int(e3.w) * 64) + lane];

      while (pos + 4 <= end) {
        ushort4 h0 = g0, h1 = g1, h2 = g2, h3 = g3;
        float4 f0 = e0, f1 = e1, f2 = e2, f3 = e3;
        if (pos + 4 < end) {  // uniform branch: prefetch only if more edges
          f0 = sea[pos + 4];
          f1 = sea[pos + 5];
          f2 = sea[pos + 6];
          f3 = sea[pos + 7];
          h0 = xlb4[(unsigned)(__float_as_int(f0.w) * 64) + lane];
          h1 = xlb4[(unsigned)(__float_as_int(f1.w) * 64) + lane];
          h2 = xlb4[(unsigned)(__float_as_int(f2.w) * 64) + lane];
          h3 = xlb4[(unsigned)(__float_as_int(f3.w) * 64) + lane];
        }
        edge_step(g0, e0, we0, we1, we2, at6, at4, xrl, num01, num23, den);
        edge_step(g1, e1, we0, we1, we2, at6, at4, xrl, num01, num23, den);
        edge_step(g2, e2, we0, we1, we2, at6, at4, xrl, num01, num23, den);
        edge_step(g3, e3, we0, we1, we2, at6, at4, xrl, num01, num23, den);
        g0 = h0; g1 = h1; g2 = h2; g3 = h3;
        e0 = f0; e1 = f1; e2 = f2; e3 = f3;
        pos += 4;
      }
      const int rem = end - pos;  // 0..3, wave-uniform
      if (rem > 0) edge_step(g0, e0, we0, we1, we2, at6, at4, xrl, num01, num23, den);
      if (rem > 1) edge_step(g1, e1, we0, we1, we2, at6, at4, xrl, num01, num23, den);
      if (rem > 2) edge_step(g2, e2, we0, we1, we2, at6, at4, xrl, num01, num23, den);
    }

    const float inv = 1.f / (den + 1e-16f);
    float4 r;
    r.x = num01.x * inv;
    r.y = num01.y * inv;
    r.z = num23.x * inv;
    r.w = num23.y * inv;
    // combine 4 heads: lanes {m, m+16, m+32, m+48} hold the same channels
    r.x += __shfl_xor(r.x, 16);
    r.y += __shfl_xor(r.y, 16);
    r.z += __shfl_xor(r.z, 16);
    r.w += __shfl_xor(r.w, 16);
    r.x += __shfl_xor(r.x, 32);
    r.y += __shfl_xor(r.y, 32);
    r.z += __shfl_xor(r.z, 32);
    r.w += __shfl_xor(r.w, 32);
    if (lane < 16) {
      float o[4];
      o[0] = 0.25f * r.x + bias4.x;
      o[1] = 0.25f * r.y + bias4.y;
      o[2] = 0.25f * r.z + bias4.z;
      o[3] = 0.25f * r.w + bias4.w;
      if (MODE == 1) {
        const float pwv[4] = {pw4.x, pw4.y, pw4.z, pw4.w};
#pragma unroll
        for (int j = 0; j < 4; ++j) o[j] = (o[j] >= 0.f) ? o[j] : pwv[j] * o[j];
        ((float4*)out)[(size_t)d * 16 + lane] = make_float4(o[0], o[1], o[2], o[3]);
      } else {
        ushort hb[4];
#pragma unroll
        for (int j = 0; j < 4; ++j) {
          __hip_bfloat16 h = __float2bfloat16(o[j]);
          hb[j] = *(ushort*)&h;
        }
        *(ushort4*)(outs + (size_t)d * 64 + 4 * lane) =
            make_ushort4(hb[0], hb[1], hb[2], hb[3]);
      }
    }
  }
}

extern "C" void kernel_launch(void* const* d_in, const int* in_sizes, int n_in,
                              void* d_out, int out_size, void* d_ws, size_t ws_size,
                              hipStream_t stream) {
  const float* x    = (const float*)d_in[0];
  const int*   ei   = (const int*)d_in[1];
  const float* ea   = (const float*)d_in[2];
  const float* Wl1  = (const float*)d_in[3];
  const float* Wr1  = (const float*)d_in[4];
  const float* We1  = (const float*)d_in[5];
  const float* att1 = (const float*)d_in[6];
  const float* b1   = (const float*)d_in[7];
  const float* Wl2  = (const float*)d_in[8];
  const float* Wr2  = (const float*)d_in[9];
  const float* We2  = (const float*)d_in[10];
  const float* att2 = (const float*)d_in[11];
  const float* b2   = (const float*)d_in[12];
  const float* pw   = (const float*)d_in[13];
  const int N_ = in_sizes[0] / 128;
  const int E_ = in_sizes[1] / 2;
  float* out = (float*)d_out;

  char* w = (char*)d_ws;
  auto alloc = [&](size_t bytes) {
    char* p = w;
    w += (bytes + 255) & ~size_t(255);
    return p;
  };
  ushort* xlb      = (ushort*)alloc((size_t)N_ * 256 * 2);   // bf16 gather operand
  ushort* xrb      = (ushort*)alloc((size_t)N_ * 256 * 2);   // bf16 logit operand
  ushort* Ax       = (ushort*)alloc((size_t)N_ * 128 * 2);   // bf16 cast of x
  ushort* h2       = (ushort*)alloc((size_t)N_ * 64 * 2);    // bf16 h (layer-2 A)
  float4* sea      = (float4*)alloc((size_t)(E_ + 8) * 16);  // {ea0,ea1,ea2,src}
  int*    deg      = (int*)alloc((size_t)N_ * 4);
  int*    rowstart = (int*)alloc((size_t)(N_ + 1) * 4);
  int*    cursor   = (int*)alloc((size_t)N_ * 4);
  int*    partial  = (int*)alloc(256 * 4);
  ushort* WT1      = (ushort*)alloc((size_t)512 * 128 * 2);
  ushort* WT2      = (ushort*)alloc((size_t)512 * 64 * 2);

  // ---- weight casts + histogram (deg zeroed via async memset) ----
  hipMemsetAsync(deg, 0, (size_t)N_ * 4, stream);
  const int wtot = 512 * 128 + 512 * 64 + E_;
  k_weights_hist<<<(wtot + 255) / 256, 256, 0, stream>>>(Wl1, Wr1, WT1, Wl2, Wr2, WT2,
                                                         ei, deg, E_);

  // ---- CSR build (2-kernel scan) + x cast + edge scatter ----
  const int nblk = (N_ + 255) / 256;
  k_scan_local<<<nblk, 256, 0, stream>>>(deg, rowstart, partial, N_);
  k_scan_final<<<nblk, 256, 0, stream>>>(partial, nblk, rowstart, cursor, sea, N_, E_);
  const int ptot = N_ * 16 + E_;
  k_prep<<<(ptot + 255) / 256, 256, 0, stream>>>(x, Ax, ei, ea, cursor, sea, N_, E_);

  const dim3 GG(4, (N_ + 127) / 128);  // x: col-blocks (xl,xl,xr,xr); y: rows
  const int chunk = 2;                 // dsts per wave
  const int FB = (N_ + chunk - 1) / chunk;  // one wave per block

  // ---- layer 1 ----
  gemm_mfma<128><<<GG, 256, 0, stream>>>(Ax, WT1, xlb, xrb, N_);
  fused_attn<0><<<FB, 64, 0, stream>>>(xlb, xrb, rowstart, sea, We1, att1,
                                       b1, pw, nullptr, h2, N_, chunk);
  // ---- layer 2 ----
  gemm_mfma<64><<<GG, 256, 0, stream>>>(h2, WT2, xlb, xrb, N_);
  fused_attn<1><<<FB, 64, 0, stream>>>(xlb, xrb, rowstart, sea, We2, att2,
                                       b2, pw, out, nullptr, N_, chunk);
}

// Round 8
// 259.238 us; speedup vs baseline: 1.3738x; 1.0081x over previous
//
#include <hip/hip_runtime.h>
#include <hip/hip_bf16.h>

#define HC 256

typedef __attribute__((ext_vector_type(8))) short bf16x8;
typedef __attribute__((ext_vector_type(4))) float f32x4;
typedef __attribute__((ext_vector_type(2))) float f32x2;

__device__ __forceinline__ void gl_lds16(const void* g, void* l) {
  __builtin_amdgcn_global_load_lds(
      (const __attribute__((address_space(1))) unsigned int*)g,
      (__attribute__((address_space(3))) unsigned int*)l, 16, 0, 0);
}

// ==== bf16 weight casts (both layers) + dst-degree histogram, one kernel ===
__device__ __forceinline__ void cast_w_one(const float* Wl, const float* Wr,
                                           ushort* WT, int F, int idx) {
  int col = idx / F, f = idx - col * F;
  float v = (col < 256) ? Wl[col * F + f] : Wr[(col - 256) * F + f];
  __hip_bfloat16 h = __float2bfloat16(v);
  WT[(size_t)col * F + f] = *(ushort*)&h;
}

__global__ void k_weights_hist(const float* __restrict__ Wl1, const float* __restrict__ Wr1,
                               ushort* __restrict__ WT1, const float* __restrict__ Wl2,
                               const float* __restrict__ Wr2, ushort* __restrict__ WT2,
                               const int* __restrict__ ei, int* __restrict__ deg, int E_) {
  int idx = blockIdx.x * blockDim.x + threadIdx.x;
  const int t1 = 512 * 128, t2 = 512 * 64;
  if (idx < t1) {
    cast_w_one(Wl1, Wr1, WT1, 128, idx);
  } else if (idx < t1 + t2) {
    cast_w_one(Wl2, Wr2, WT2, 64, idx - t1);
  } else {
    int e = idx - t1 - t2;
    if (e < E_) atomicAdd(&deg[ei[E_ + e]], 1);
  }
}

// ======== MFMA GEMM: single 32KB stage buffer, sequential K-steps ==========
// 4 waves, 128x128 block tile, 64x64 wave tile, BK=64. LDS 34.8KB.
template <int F>
__global__ __launch_bounds__(256) void gemm_mfma(const ushort* __restrict__ A,
                                                 const ushort* __restrict__ WT,
                                                 ushort* __restrict__ xlb,
                                                 ushort* __restrict__ xrb, int n_nodes) {
  constexpr int NSTEP = F / 64;
  constexpr int SM = 17408;  // epilogue Ct (128 x pitch136) > stage 16384
  __shared__ __align__(16) ushort smem[SM];
  const int tid = threadIdx.x;
  const int wv = tid >> 6, lane = tid & 63;
  const int m16 = lane & 15, quad = lane >> 4;
  const int col0 = blockIdx.x * 128;  // 0,1 -> xl ; 2,3 -> xr
  const int row0 = blockIdx.y * 128;
  const int wm = (wv >> 1) * 64, wn = (wv & 1) * 64;

  f32x4 acc[4][4];
#pragma unroll
  for (int i = 0; i < 4; ++i)
#pragma unroll
    for (int j = 0; j < 4; ++j) acc[i][j] = (f32x4){0.f, 0.f, 0.f, 0.f};

  ushort* As = smem;
  ushort* Bs = smem + 8192;

  auto load_step = [&](int s) {
    const int khat = s * 64;
#pragma unroll
    for (int t = 0; t < 4; ++t) {
      const int sl16 = tid + 256 * t;  // LDS slot (16B units), linear in lane
      const int row = sl16 >> 3, sl = sl16 & 7;
      const int gch = sl ^ (row & 7);  // swizzle on the GLOBAL address
      const int grow = row0 + row;
      if (grow < n_nodes)
        gl_lds16(A + (size_t)grow * F + khat + gch * 8, As + sl16 * 8);
      gl_lds16(WT + (size_t)(col0 + row) * F + khat + gch * 8, Bs + sl16 * 8);
    }
  };

  auto mfma_step = [&]() {
#pragma unroll
    for (int kh = 0; kh < 2; ++kh) {
      bf16x8 af[4], bf[4];
#pragma unroll
      for (int i = 0; i < 4; ++i) {
        const int row = wm + i * 16 + m16;
        const int slot = (kh * 4 + quad) ^ (row & 7);
        af[i] = *(bf16x8*)&As[row * 64 + slot * 8];
      }
#pragma unroll
      for (int j = 0; j < 4; ++j) {
        const int col = wn + j * 16 + m16;
        const int slot = (kh * 4 + quad) ^ (col & 7);
        bf[j] = *(bf16x8*)&Bs[col * 64 + slot * 8];
      }
#pragma unroll
      for (int i = 0; i < 4; ++i)
#pragma unroll
        for (int j = 0; j < 4; ++j)
          acc[i][j] =
              __builtin_amdgcn_mfma_f32_16x16x32_bf16(af[i], bf[j], acc[i][j], 0, 0, 0);
    }
  };

  load_step(0);
  __syncthreads();
  mfma_step();
  if (NSTEP > 1) {
    __syncthreads();  // all LDS reads of step 0 done before overwrite
    load_step(1);
    __syncthreads();  // drains step-1 DMAs
    mfma_step();
  }

  // ---- epilogue: acc -> bf16 -> LDS (pitch 136) -> coalesced 16B stores ----
  __syncthreads();  // all LDS reads done; safe to alias with Ct
  ushort* Ct = smem;
#pragma unroll
  for (int i = 0; i < 4; ++i) {
#pragma unroll
    for (int r = 0; r < 4; ++r) {
      const int row = wm + i * 16 + quad * 4 + r;
#pragma unroll
      for (int j = 0; j < 4; ++j) {
        __hip_bfloat16 h = __float2bfloat16(acc[i][j][r]);
        Ct[row * 136 + wn + j * 16 + m16] = *(ushort*)&h;
      }
    }
  }
  __syncthreads();
  const bool is_xl = (col0 < 256);
  ushort* dst = is_xl ? xlb : xrb;
  const int cb = is_xl ? col0 : (col0 - 256);
  const int chunk = tid & 15;  // 16B chunk within the 256B row
#pragma unroll
  for (int it = 0; it < 8; ++it) {
    const int row = (tid >> 4) + 16 * it;
    const int grow = row0 + row;
    int4 v = *(int4*)&Ct[row * 136 + chunk * 8];
    if (grow < n_nodes)
      *(int4*)(dst + (size_t)grow * 256 + cb + chunk * 8) = v;
  }
}

// ================= CSR build (edges bucketed by dst) =======================
__global__ void k_scan_local(const int* __restrict__ deg, int* __restrict__ rowstart,
                             int* __restrict__ partial, int n) {
  __shared__ int a[256], b[256];
  const int t = threadIdx.x;
  const int i = blockIdx.x * 256 + t;
  const int v = (i < n) ? deg[i] : 0;
  a[t] = v;
  __syncthreads();
  int* cur = a;
  int* nxt = b;
  for (int off = 1; off < 256; off <<= 1) {
    int x = cur[t];
    if (t >= off) x += cur[t - off];
    nxt[t] = x;
    __syncthreads();
    int* tmp = cur; cur = nxt; nxt = tmp;
  }
  const int incl = cur[t];
  if (i < n) rowstart[i] = incl - v;
  if (t == 255) partial[blockIdx.x] = incl;
}

// merged: every block redundantly scans the block-sums (nblk<=256), adds its
// exclusive prefix, writes rowstart+cursor; block 0 zero-fills the CSR pad.
__global__ void k_scan_final(const int* __restrict__ partial, int nblk,
                             int* __restrict__ rowstart, int* __restrict__ cursor,
                             float4* __restrict__ sea, int n, int E_) {
  __shared__ int a[256], b[256];
  const int t = threadIdx.x;
  const int v = (t < nblk) ? partial[t] : 0;
  a[t] = v;
  __syncthreads();
  int* cur = a;
  int* nxt = b;
  for (int off = 1; off < 256; off <<= 1) {
    int x = cur[t];
    if (t >= off) x += cur[t - off];
    nxt[t] = x;
    __syncthreads();
    int* tmp = cur; cur = nxt; nxt = tmp;
  }
  const int boff = (blockIdx.x > 0) ? cur[blockIdx.x - 1] : 0;
  const int i = blockIdx.x * 256 + t;
  if (i < n) {
    int vv = rowstart[i] + boff;
    rowstart[i] = vv;
    cursor[i] = vv;
  }
  if (i == 0) rowstart[n] = E_;
  if (blockIdx.x == 0 && t < 8) sea[E_ + t] = make_float4(0.f, 0.f, 0.f, 0.f);
}

// ==== fused: cast x -> bf16 A AND CSR edge scatter (src packed in sea.w) ===
// sea.w now carries the BYTE offset of the src row in xlb (src << 9):
// the attn gather becomes base + (off + lane*8), one 32-bit add per gather.
__global__ void k_prep(const float* __restrict__ x, ushort* __restrict__ A,
                       const int* __restrict__ ei, const float* __restrict__ ea,
                       int* __restrict__ cursor, float4* __restrict__ sea,
                       int n, int E_) {
  const int nx8 = n * 16;  // 8 elements per thread
  int idx = blockIdx.x * blockDim.x + threadIdx.x;
  if (idx < nx8) {
    const float4* xp = (const float4*)x + (size_t)idx * 2;
    float4 v0 = xp[0], v1 = xp[1];
    float vv[8] = {v0.x, v0.y, v0.z, v0.w, v1.x, v1.y, v1.z, v1.w};
    __align__(16) ushort hb[8];
#pragma unroll
    for (int j = 0; j < 8; ++j) {
      __hip_bfloat16 h = __float2bfloat16(vv[j]);
      hb[j] = *(ushort*)&h;
    }
    *(int4*)(A + (size_t)idx * 8) = *(int4*)hb;
  } else {
    int e = idx - nx8;
    if (e < E_) {
      int dst = ei[E_ + e];
      int pos = atomicAdd(&cursor[dst], 1);
      sea[pos] = make_float4(ea[e * 3], ea[e * 3 + 1], ea[e * 3 + 2],
                             __int_as_float(ei[e] << 9));  // byte offset
    }
  }
}

// ================= fused per-destination attention =========================
// ONE wave per workgroup; chunk dsts per wave; 4-edge software pipeline.
// sea.w carries the src-row BYTE offset. pos/end readfirstlane'd so the
// sea[] edge-record loads are provably wave-uniform (scalar s_load path).
// Logit: att·lrelu(s) = 0.6att·s + 0.4att·|s|, pre-scaled by log2(e) so
// w = exp2(p). 16-lane head reduce via DPP row_ror adds (pure VALU).
__device__ __forceinline__ float dpp_ror_add(float p) {
  p += __int_as_float(__builtin_amdgcn_update_dpp(
      0, __float_as_int(p), 0x128, 0xF, 0xF, true));  // row_ror:8
  p += __int_as_float(__builtin_amdgcn_update_dpp(
      0, __float_as_int(p), 0x124, 0xF, 0xF, true));  // row_ror:4
  p += __int_as_float(__builtin_amdgcn_update_dpp(
      0, __float_as_int(p), 0x122, 0xF, 0xF, true));  // row_ror:2
  p += __int_as_float(__builtin_amdgcn_update_dpp(
      0, __float_as_int(p), 0x121, 0xF, 0xF, true));  // row_ror:1
  return p;
}

__device__ __forceinline__ void edge_step(
    const ushort4& lu, const float4& eav, const f32x2* we0, const f32x2* we1,
    const f32x2* we2, const f32x2* at6, const f32x2* at4, const f32x2* xrl,
    f32x2& num01, f32x2& num23, float& den) {
  f32x2 lav0, lav1;
  lav0.x = __uint_as_float((unsigned)lu.x << 16);
  lav0.y = __uint_as_float((unsigned)lu.y << 16);
  lav1.x = __uint_as_float((unsigned)lu.z << 16);
  lav1.y = __uint_as_float((unsigned)lu.w << 16);
  f32x2 pv = {0.f, 0.f};
#pragma unroll
  for (int j = 0; j < 2; ++j) {
    f32x2 la = (j == 0) ? lav0 : lav1;
    f32x2 t = xrl[j] + we0[j] * eav.x;   // fma chain rooted at xr (folds adds)
    t = t + we1[j] * eav.y;
    t = t + we2[j] * eav.z;
    f32x2 s = t + la;
    f32x2 sa = {fabsf(s.x), fabsf(s.y)}; // |s|: VOP3 input modifier, free
    pv = pv + at6[j] * s;
    pv = pv + at4[j] * sa;
  }
  float p = pv.x + pv.y;
  p = dpp_ror_add(p);          // sum over the 16-lane head group
  const float w = exp2f(p);    // at6/at4 carry log2(e); |logit| small
  den += w;
  num01 = num01 + (f32x2){w, w} * lav0;
  num23 = num23 + (f32x2){w, w} * lav1;
}

template <int MODE>
__global__ __launch_bounds__(64) void fused_attn(
    const ushort* __restrict__ xlb, const ushort* __restrict__ xrb,
    const int* __restrict__ rowstart, const float4* __restrict__ sea,
    const float* __restrict__ We, const float* __restrict__ att,
    const float* __restrict__ bias, const float* __restrict__ pw,
    float* __restrict__ out, ushort* __restrict__ outs, int n, int chunk) {
  const int lane = threadIdx.x;
  const int d0 = blockIdx.x * chunk;
  if (d0 >= n) return;
  const int d1 = min(d0 + chunk, n);

  // ---- prologue (amortized over the chunk) ----
  f32x2 we0[2], we1[2], we2[2], at6[2], at4[2];
  const float L2E = 1.4426950408889634f;
#pragma unroll
  for (int j = 0; j < 4; ++j) {
    int r = 4 * lane + j;
    ((float*)we0)[j] = We[r * 3 + 0];
    ((float*)we1)[j] = We[r * 3 + 1];
    ((float*)we2)[j] = We[r * 3 + 2];
    float a = att[r];
    ((float*)at6)[j] = a * (0.6f * L2E);
    ((float*)at4)[j] = a * (0.4f * L2E);
  }
  const float4 bias4 = ((const float4*)bias)[lane & 15];
  float4 pw4 = {0.f, 0.f, 0.f, 0.f};
  if (MODE == 1) pw4 = ((const float4*)pw)[lane & 15];
  const char* xlbB = (const char*)xlb;
  const unsigned lane8 = (unsigned)lane * 8u;

#define GAT(e_) (*(const ushort4*)(xlbB + ((unsigned)__float_as_int((e_).w) + lane8)))

  for (int d = d0; d < d1; ++d) {
    const ushort4 xu = ((const ushort4*)xrb)[(unsigned)(d * 64) + lane];
    f32x2 xrl[2];
    xrl[0].x = __uint_as_float((unsigned)xu.x << 16);
    xrl[0].y = __uint_as_float((unsigned)xu.y << 16);
    xrl[1].x = __uint_as_float((unsigned)xu.z << 16);
    xrl[1].y = __uint_as_float((unsigned)xu.w << 16);

    // wave-uniform CSR bounds: readfirstlane makes uniformity explicit so
    // the sea[] edge records go through the scalar (SMEM) path.
    int pos = __builtin_amdgcn_readfirstlane(rowstart[d]);
    const int end = __builtin_amdgcn_readfirstlane(rowstart[d + 1]);
    f32x2 num01 = {0.f, 0.f}, num23 = {0.f, 0.f};
    float den = 0.f;

    if (pos < end) {
      // CSR padded by 8 zero entries past E: over-read safe; pad/next-dst
      // entries are fetched but never processed. src byte-offset in sea.w.
      float4 e0 = sea[pos], e1 = sea[pos + 1], e2 = sea[pos + 2], e3 = sea[pos + 3];
      ushort4 g0 = GAT(e0), g1 = GAT(e1), g2 = GAT(e2), g3 = GAT(e3);

      while (pos + 4 <= end) {
        ushort4 h0 = g0, h1 = g1, h2 = g2, h3 = g3;
        float4 f0 = e0, f1 = e1, f2 = e2, f3 = e3;
        if (pos + 4 < end) {  // uniform branch: prefetch only if more edges
          f0 = sea[pos + 4];
          f1 = sea[pos + 5];
          f2 = sea[pos + 6];
          f3 = sea[pos + 7];
          h0 = GAT(f0); h1 = GAT(f1); h2 = GAT(f2); h3 = GAT(f3);
        }
        edge_step(g0, e0, we0, we1, we2, at6, at4, xrl, num01, num23, den);
        edge_step(g1, e1, we0, we1, we2, at6, at4, xrl, num01, num23, den);
        edge_step(g2, e2, we0, we1, we2, at6, at4, xrl, num01, num23, den);
        edge_step(g3, e3, we0, we1, we2, at6, at4, xrl, num01, num23, den);
        g0 = h0; g1 = h1; g2 = h2; g3 = h3;
        e0 = f0; e1 = f1; e2 = f2; e3 = f3;
        pos += 4;
      }
      const int rem = end - pos;  // 0..3, wave-uniform
      if (rem > 0) edge_step(g0, e0, we0, we1, we2, at6, at4, xrl, num01, num23, den);
      if (rem > 1) edge_step(g1, e1, we0, we1, we2, at6, at4, xrl, num01, num23, den);
      if (rem > 2) edge_step(g2, e2, we0, we1, we2, at6, at4, xrl, num01, num23, den);
    }

    const float inv = 1.f / (den + 1e-16f);
    float4 r;
    r.x = num01.x * inv;
    r.y = num01.y * inv;
    r.z = num23.x * inv;
    r.w = num23.y * inv;
    // combine 4 heads: lanes {m, m+16, m+32, m+48} hold the same channels
    r.x += __shfl_xor(r.x, 16);
    r.y += __shfl_xor(r.y, 16);
    r.z += __shfl_xor(r.z, 16);
    r.w += __shfl_xor(r.w, 16);
    r.x += __shfl_xor(r.x, 32);
    r.y += __shfl_xor(r.y, 32);
    r.z += __shfl_xor(r.z, 32);
    r.w += __shfl_xor(r.w, 32);
    if (lane < 16) {
      float o[4];
      o[0] = 0.25f * r.x + bias4.x;
      o[1] = 0.25f * r.y + bias4.y;
      o[2] = 0.25f * r.z + bias4.z;
      o[3] = 0.25f * r.w + bias4.w;
      if (MODE == 1) {
        const float pwv[4] = {pw4.x, pw4.y, pw4.z, pw4.w};
#pragma unroll
        for (int j = 0; j < 4; ++j) o[j] = (o[j] >= 0.f) ? o[j] : pwv[j] * o[j];
        ((float4*)out)[(size_t)d * 16 + lane] = make_float4(o[0], o[1], o[2], o[3]);
      } else {
        ushort hb[4];
#pragma unroll
        for (int j = 0; j < 4; ++j) {
          __hip_bfloat16 h = __float2bfloat16(o[j]);
          hb[j] = *(ushort*)&h;
        }
        *(ushort4*)(outs + (size_t)d * 64 + 4 * lane) =
            make_ushort4(hb[0], hb[1], hb[2], hb[3]);
      }
    }
  }
#undef GAT
}

extern "C" void kernel_launch(void* const* d_in, const int* in_sizes, int n_in,
                              void* d_out, int out_size, void* d_ws, size_t ws_size,
                              hipStream_t stream) {
  const float* x    = (const float*)d_in[0];
  const int*   ei   = (const int*)d_in[1];
  const float* ea   = (const float*)d_in[2];
  const float* Wl1  = (const float*)d_in[3];
  const float* Wr1  = (const float*)d_in[4];
  const float* We1  = (const float*)d_in[5];
  const float* att1 = (const float*)d_in[6];
  const float* b1   = (const float*)d_in[7];
  const float* Wl2  = (const float*)d_in[8];
  const float* Wr2  = (const float*)d_in[9];
  const float* We2  = (const float*)d_in[10];
  const float* att2 = (const float*)d_in[11];
  const float* b2   = (const float*)d_in[12];
  const float* pw   = (const float*)d_in[13];
  const int N_ = in_sizes[0] / 128;
  const int E_ = in_sizes[1] / 2;
  float* out = (float*)d_out;

  char* w = (char*)d_ws;
  auto alloc = [&](size_t bytes) {
    char* p = w;
    w += (bytes + 255) & ~size_t(255);
    return p;
  };
  ushort* xlb      = (ushort*)alloc((size_t)N_ * 256 * 2);   // bf16 gather operand
  ushort* xrb      = (ushort*)alloc((size_t)N_ * 256 * 2);   // bf16 logit operand
  ushort* Ax       = (ushort*)alloc((size_t)N_ * 128 * 2);   // bf16 cast of x
  ushort* h2       = (ushort*)alloc((size_t)N_ * 64 * 2);    // bf16 h (layer-2 A)
  float4* sea      = (float4*)alloc((size_t)(E_ + 8) * 16);  // {ea0,ea1,ea2,srcB}
  int*    deg      = (int*)alloc((size_t)N_ * 4);
  int*    rowstart = (int*)alloc((size_t)(N_ + 1) * 4);
  int*    cursor   = (int*)alloc((size_t)N_ * 4);
  int*    partial  = (int*)alloc(256 * 4);
  ushort* WT1      = (ushort*)alloc((size_t)512 * 128 * 2);
  ushort* WT2      = (ushort*)alloc((size_t)512 * 64 * 2);

  // ---- weight casts + histogram (deg zeroed via async memset) ----
  hipMemsetAsync(deg, 0, (size_t)N_ * 4, stream);
  const int wtot = 512 * 128 + 512 * 64 + E_;
  k_weights_hist<<<(wtot + 255) / 256, 256, 0, stream>>>(Wl1, Wr1, WT1, Wl2, Wr2, WT2,
                                                         ei, deg, E_);

  // ---- CSR build (2-kernel scan) + x cast + edge scatter ----
  const int nblk = (N_ + 255) / 256;
  k_scan_local<<<nblk, 256, 0, stream>>>(deg, rowstart, partial, N_);
  k_scan_final<<<nblk, 256, 0, stream>>>(partial, nblk, rowstart, cursor, sea, N_, E_);
  const int ptot = N_ * 16 + E_;
  k_prep<<<(ptot + 255) / 256, 256, 0, stream>>>(x, Ax, ei, ea, cursor, sea, N_, E_);

  const dim3 GG(4, (N_ + 127) / 128);  // x: col-blocks (xl,xl,xr,xr); y: rows
  const int chunk = 2;                 // dsts per wave
  const int FB = (N_ + chunk - 1) / chunk;  // one wave per block

  // ---- layer 1 ----
  gemm_mfma<128><<<GG, 256, 0, stream>>>(Ax, WT1, xlb, xrb, N_);
  fused_attn<0><<<FB, 64, 0, stream>>>(xlb, xrb, rowstart, sea, We1, att1,
                                       b1, pw, nullptr, h2, N_, chunk);
  // ---- layer 2 ----
  gemm_mfma<64><<<GG, 256, 0, stream>>>(h2, WT2, xlb, xrb, N_);
  fused_attn<1><<<FB, 64, 0, stream>>>(xlb, xrb, rowstart, sea, We2, att2,
                                       b2, pw, out, nullptr, N_, chunk);
}